// Round 9
// baseline (11.391 us; speedup 1.0000x reference)
//
#include <hip/hip_runtime.h>
#include <hip/hip_bf16.h>
#include <math.h>

// BatchAllTripletLoss — bf16-MFMA Gram engine v3: 2 blocks/CU + HW cvt_pk.
// batch = concat(h1,h2) : (512, 256) f32.
// Masked triplet only at k=j^256:
//   t(i,j) = relu((sq_j - sq_jp) - 2*(dot_ij - dot_ijp) + 1)   [sq_i cancels]
// outputs: loss, mean(differences)=0 (exact), good, bad, sqrt(mean(sq))
//
// Lessons encoded:
//  r3: no __threadfence/atomic finalize (~40us) -> tiny second kernel.
//  r6: f32 VALU engine floor ~10us -> MFMA dot engine.
//  r8: in-register pair exchange (D col = lane&15 -> __shfl_xor(acc,8)).
//  r9: 512 blocks x 128 thr (2 blocks/CU -> staging/MFMA phase overlap,
//      m114) + v_cvt_pk_bf16_f32 via __float22bfloat162_rn (m240).
//
// MFMA 16x16x32 bf16 layouts (measured, m89/m91):
//   A frag: lane l holds row l&15, k chunk 8*(l>>4)..+7   (s16x8)
//   B frag: lane l holds col l&15, same k chunk
//   D frag: col = lane&15, row = (lane>>4)*4 + reg
// LDS tiles [rows][256 bf16], k-group swizzle g^=(row&7) -> <=2-way (free).

typedef short s16x8 __attribute__((ext_vector_type(8)));
typedef float f32x4 __attribute__((ext_vector_type(4)));

__device__ __forceinline__ const float* batch_row(const float* __restrict__ h1,
                                                  const float* __restrict__ h2,
                                                  int r) {
    return (r < 256) ? (h1 + (size_t)r * 256) : (h2 + (size_t)(r - 256) * 256);
}

__device__ __forceinline__ s16x8 pack8(float4 lo, float4 hi) {   // 4x v_cvt_pk_bf16_f32
    union { __hip_bfloat162 h2[4]; s16x8 v; } u;
    u.h2[0] = __float22bfloat162_rn(make_float2(lo.x, lo.y));
    u.h2[1] = __float22bfloat162_rn(make_float2(lo.z, lo.w));
    u.h2[2] = __float22bfloat162_rn(make_float2(hi.x, hi.y));
    u.h2[3] = __float22bfloat162_rn(make_float2(hi.z, hi.w));
    return u.v;
}

__device__ __forceinline__ float hsum4(float4 v) { return (v.x + v.y) + (v.z + v.w); }

// --- K1: MFMA Gram + pair stats + f32 sq emission -------------------------
__global__ __launch_bounds__(128) void gramstats_kernel(const float* __restrict__ h1,
                                                        const float* __restrict__ h2,
                                                        float* __restrict__ sq,
                                                        float* __restrict__ partials) {
    const int ib = blockIdx.x >> 5;  // 0..15 -> A rows 32ib..32ib+31
    const int jb = blockIdx.x & 31;  // 0..31 -> B cols 8jb..+7 (rows 0-7) and +256 (rows 8-15)
    const int t  = threadIdx.x;      // 0..127

    __shared__ __align__(16) unsigned short tileA[32 * 256];  // 16 KB
    __shared__ __align__(16) unsigned short tileB[16 * 256];  //  8 KB
    __shared__ float sqB[16];
    __shared__ float red[3][2];

    // --- stage A: 32 rows, f32 -> bf16, swizzled (8 groups/thread) --------
#pragma unroll
    for (int p = 0; p < 8; ++p) {
        const int idx = p * 128 + t;
        const int row = idx >> 5, g = idx & 31;          // 32 k-groups of 8 per row
        const float4* Ap = reinterpret_cast<const float4*>(batch_row(h1, h2, ib * 32 + row));
        const int gs = (g ^ (row & 7)) * 8;
        *reinterpret_cast<s16x8*>(&tileA[row * 256 + gs]) = pack8(Ap[2 * g], Ap[2 * g + 1]);
    }
    // --- stage B: 16 rows (8 j-cols + 8 pairs) + f32 sq on the fly --------
#pragma unroll
    for (int p = 0; p < 4; ++p) {
        const int idx = p * 128 + t;
        const int row = idx >> 5, g = idx & 31;          // 32 threads per row
        const int col = jb * 8 + (row & 7) + ((row & 8) << 5);   // +256 for rows 8-15
        const float4* Bp = reinterpret_cast<const float4*>(batch_row(h1, h2, col));
        const float4 lo = Bp[2 * g], hi = Bp[2 * g + 1];
        const int gs = (g ^ (row & 7)) * 8;
        *reinterpret_cast<s16x8*>(&tileB[row * 256 + gs]) = pack8(lo, hi);
        float s = lo.x * lo.x + lo.y * lo.y + lo.z * lo.z + lo.w * lo.w
                + hi.x * hi.x + hi.y * hi.y + hi.z * hi.z + hi.w * hi.w;
        s += __shfl_xor(s, 1);  s += __shfl_xor(s, 2);  s += __shfl_xor(s, 4);
        s += __shfl_xor(s, 8);  s += __shfl_xor(s, 16);          // 32-lane group reduce
        if ((t & 31) == 0) {
            sqB[row] = s;
            if (ib == 0) sq[col] = s;                            // each col exactly once
        }
    }
    __syncthreads();

    // --- MFMA: wave w = row-half rh; 16 A-rows x all 16 B cols ------------
    const int lane = t & 63, w = t >> 6;   // w = rh 0..1
    const int ar = w * 16 + (lane & 15);
    const int br = lane & 15;
    const int kc = lane >> 4;              // 0..3
    f32x4 acc = {0.f, 0.f, 0.f, 0.f};
#pragma unroll
    for (int s = 0; s < 8; ++s) {
        const int ga = ((s * 4 + kc) ^ (ar & 7)) * 8;
        const int gb = ((s * 4 + kc) ^ (br & 7)) * 8;
        const s16x8 av = *reinterpret_cast<const s16x8*>(&tileA[ar * 256 + ga]);
        const s16x8 bv = *reinterpret_cast<const s16x8*>(&tileB[br * 256 + gb]);
        acc = __builtin_amdgcn_mfma_f32_16x16x32_bf16(av, bv, acc, 0, 0, 0);
    }

    // --- stats: pair dot lives in lane^8 (D col = lane&15) ----------------
    const int n = lane & 15;
    const float dsq = sqB[n] - sqB[n ^ 8];               // sq_col - sq_pair
    float srel = 0.f, crel = 0.f, good = 0.f;
#pragma unroll
    for (int r = 0; r < 4; ++r) {
        const float dotp = __shfl_xor(acc[r], 8);        // dot(i, pair col)
        const float diff = dsq - 2.f * (acc[r] - dotp);
        const float tv = fmaxf(diff + 1.f, 0.f);
        srel += (tv > 1e-5f) ? tv : 0.f;
        crel += (tv > 1e-5f);
        good += (tv < 1e-5f);
    }

#pragma unroll
    for (int off = 32; off > 0; off >>= 1) {
        srel += __shfl_down(srel, off);
        crel += __shfl_down(crel, off);
        good += __shfl_down(good, off);
    }
    if ((t & 63) == 0) { red[0][w] = srel; red[1][w] = crel; red[2][w] = good; }
    __syncthreads();
    if (t == 0) {
        reinterpret_cast<float4*>(partials)[blockIdx.x] =
            make_float4(red[0][0] + red[0][1],
                        red[1][0] + red[1][1],
                        red[2][0] + red[2][1], 0.f);
    }
}

// --- K2: single-wave finalize + all 5 outputs -----------------------------
__global__ __launch_bounds__(64) void finalize_kernel(const float* __restrict__ sq,
                                                      const float* __restrict__ partials,
                                                      float* __restrict__ out) {
    const int t = threadIdx.x;   // 0..63
    float s = 0.f, c = 0.f, g = 0.f, q = 0.f;
    const float4* P = reinterpret_cast<const float4*>(partials);
#pragma unroll
    for (int p = 0; p < 8; ++p) {                 // 512 partials
        const float4 v = P[t + 64 * p];
        s += v.x; c += v.y; g += v.z;
    }
    const float4* S = reinterpret_cast<const float4*>(sq);
#pragma unroll
    for (int p = 0; p < 2; ++p)                   // 512 sq values
        q += hsum4(S[t + 64 * p]);
#pragma unroll
    for (int off = 32; off > 0; off >>= 1) {
        s += __shfl_down(s, off);
        c += __shfl_down(c, off);
        g += __shfl_down(g, off);
        q += __shfl_down(q, off);
    }
    if (t == 0) {
        const float mean_sq  = q / 512.0f;
        const float mean_rel = s / c;
        const float goodTot  = 133955584.0f + g;    // (512^3 - 512^2) + good_masked
        out[0] = mean_rel + 1e-4f * mean_sq;        // loss
        out[1] = 0.0f;                              // mean(differences): exact cancellation
        out[2] = goodTot;                           // good
        out[3] = 134217728.0f - goodTot;            // bad
        out[4] = sqrtf(mean_sq);                    // sqrt(mean norm^2)
    }
}

extern "C" void kernel_launch(void* const* d_in, const int* in_sizes, int n_in,
                              void* d_out, int out_size, void* d_ws, size_t ws_size,
                              hipStream_t stream) {
    (void)in_sizes; (void)n_in; (void)out_size; (void)ws_size;
    const float* h1 = (const float*)d_in[0];
    const float* h2 = (const float*)d_in[1];
    // d_in[2] (h3) unused by the reference forward.
    char* ws = (char*)d_ws;
    float* sq       = (float*)ws;              // 512 floats
    float* partials = (float*)(ws + 4096);     // 512 x float4
    float* out      = (float*)d_out;

    gramstats_kernel<<<512, 128, 0, stream>>>(h1, h2, sq, partials);
    finalize_kernel <<<1,   64,  0, stream>>>(sq, partials, out);
}